// Round 1
// baseline (536.113 us; speedup 1.0000x reference)
//
#include <hip/hip_runtime.h>
#include <hip/hip_bf16.h>

#define DEVI __device__ __forceinline__

typedef __attribute__((ext_vector_type(8))) short bf16x8;
typedef __attribute__((ext_vector_type(4))) float f32x4;
typedef __attribute__((ext_vector_type(4))) unsigned short us4;

DEVI unsigned short f2bf(float f) {
  union { float f; unsigned u; } v; v.f = f;
  unsigned r = v.u + 0x7fffu + ((v.u >> 16) & 1u);
  return (unsigned short)(r >> 16);
}
DEVI float bf2f(unsigned short h) {
  union { unsigned u; float f; } v; v.u = ((unsigned)h) << 16;
  return v.f;
}

// ---------------- elementwise split x -> x_hi, x_lo ----------------
__global__ void __launch_bounds__(256) k_convert_split(
    const float* __restrict__ x, unsigned short* __restrict__ hi,
    unsigned short* __restrict__ lo, int n4) {
  int i = blockIdx.x * 256 + threadIdx.x;
  if (i >= n4) return;
  float4 v = reinterpret_cast<const float4*>(x)[i];
  float vv[4] = {v.x, v.y, v.z, v.w};
  us4 h, l;
#pragma unroll
  for (int j = 0; j < 4; ++j) {
    unsigned short hh = f2bf(vv[j]);
    h[j] = hh;
    l[j] = f2bf(vv[j] - bf2f(hh));
  }
  reinterpret_cast<us4*>(hi)[i] = h;
  reinterpret_cast<us4*>(lo)[i] = l;
}

// ---------------- transpose weight [K][N] -> WT[N][K] (bf16 hi / optional lo) ----
__global__ void __launch_bounds__(256) k_transpose_split(
    const float* __restrict__ W, unsigned short* __restrict__ Thi,
    unsigned short* __restrict__ Tlo, int n, int split) {
  __shared__ float t[32][33];
  int tx = threadIdx.x & 31, ty = threadIdx.x >> 5;
  int n0 = blockIdx.x * 32, k0 = blockIdx.y * 32;
#pragma unroll
  for (int r = 0; r < 4; ++r)
    t[ty + r * 8][tx] = W[(size_t)(k0 + ty + r * 8) * n + n0 + tx];
  __syncthreads();
#pragma unroll
  for (int r = 0; r < 4; ++r) {
    int nn = n0 + ty + r * 8;
    float v = t[tx][ty + r * 8];
    unsigned short hh = f2bf(v);
    Thi[(size_t)nn * n + k0 + tx] = hh;
    if (split) Tlo[(size_t)nn * n + k0 + tx] = f2bf(v - bf2f(hh));
  }
}

// ---------------- GEMM: C[M][N] = A[M][K] * B_T[N][K]  (both bf16, contiguous K)
// SPLIT=1: A,B given as (hi,lo) pairs; acc = Ah*Bh + Ah*Bl + Al*Bh  (fp32-quality)
// EPI: 0 = bias + write split hi/lo bf16 (proj q,k)
//      1 = bias + write bf16 transposed to v_t[b][d][s]  (proj v)
//      2 = write fp32 (scores)
//      3 = write bf16 (attn = P*V)
//      4 = bias + residual + write fp32 (out proj)
DEVI void stage_tile(unsigned short* lbase, const unsigned short* g, int ldg,
                     int wid, int lane) {
#pragma unroll
  for (int it = 0; it < 2; ++it) {
    int chunk = it * 256 + wid * 64 + lane;
    int r = chunk >> 2, c = (chunk & 3) * 8;
    const unsigned short* gp = g + (size_t)r * ldg + c;
    unsigned short* lp = lbase + (it * 256 + wid * 64) * 8;  // wave-uniform
    __builtin_amdgcn_global_load_lds(
        (const __attribute__((address_space(1))) unsigned int*)gp,
        (__attribute__((address_space(3))) unsigned int*)lp, 16, 0, 0);
  }
}

template <int SPLIT, int EPI>
__global__ void __launch_bounds__(256, 2) k_gemm(
    const unsigned short* __restrict__ Ahi, const unsigned short* __restrict__ Alo,
    const unsigned short* __restrict__ Bhi, const unsigned short* __restrict__ Blo,
    int M, int N, int K,
    const float* __restrict__ bias, const float* __restrict__ resid,
    float* __restrict__ outF, unsigned short* __restrict__ outH,
    unsigned short* __restrict__ outL, int ldc) {
  __shared__ unsigned short lds[(SPLIT ? 4 : 2) * 4096];
  unsigned short* Ah = lds;
  unsigned short* Al = SPLIT ? (lds + 4096) : lds;
  unsigned short* Bh = lds + (SPLIT ? 2 : 1) * 4096;
  unsigned short* Bl = SPLIT ? (lds + 3 * 4096) : lds;

  const int tid = threadIdx.x, lane = tid & 63, wid = tid >> 6;
  const int wr = (wid >> 1) * 64, wc = (wid & 1) * 64;
  const int lc = lane & 15, lr = lane >> 4;
  const size_t row0 = (size_t)blockIdx.x * 128, col0 = (size_t)blockIdx.y * 128;

  const unsigned short* Agh = Ahi + row0 * K;
  const unsigned short* Agl = SPLIT ? (Alo + row0 * K) : nullptr;
  const unsigned short* Bgh = Bhi + col0 * K;
  const unsigned short* Bgl = SPLIT ? (Blo + col0 * K) : nullptr;

  f32x4 acc[4][4] = {};

  for (int k0 = 0; k0 < K; k0 += 32) {
    stage_tile(Ah, Agh + k0, K, wid, lane);
    stage_tile(Bh, Bgh + k0, K, wid, lane);
    if (SPLIT) {
      stage_tile(Al, Agl + k0, K, wid, lane);
      stage_tile(Bl, Bgl + k0, K, wid, lane);
    }
    __syncthreads();
    bf16x8 ah[4], bh[4], al[4], bl[4];
#pragma unroll
    for (int i = 0; i < 4; ++i) {
      ah[i] = *reinterpret_cast<const bf16x8*>(Ah + (wr + i * 16 + lc) * 32 + lr * 8);
      bh[i] = *reinterpret_cast<const bf16x8*>(Bh + (wc + i * 16 + lc) * 32 + lr * 8);
      if (SPLIT) {
        al[i] = *reinterpret_cast<const bf16x8*>(Al + (wr + i * 16 + lc) * 32 + lr * 8);
        bl[i] = *reinterpret_cast<const bf16x8*>(Bl + (wc + i * 16 + lc) * 32 + lr * 8);
      }
    }
#pragma unroll
    for (int mi = 0; mi < 4; ++mi)
#pragma unroll
      for (int ni = 0; ni < 4; ++ni) {
        acc[mi][ni] = __builtin_amdgcn_mfma_f32_16x16x32_bf16(ah[mi], bh[ni], acc[mi][ni], 0, 0, 0);
        if (SPLIT) {
          acc[mi][ni] = __builtin_amdgcn_mfma_f32_16x16x32_bf16(ah[mi], bl[ni], acc[mi][ni], 0, 0, 0);
          acc[mi][ni] = __builtin_amdgcn_mfma_f32_16x16x32_bf16(al[mi], bh[ni], acc[mi][ni], 0, 0, 0);
        }
      }
    __syncthreads();
  }

#pragma unroll
  for (int mi = 0; mi < 4; ++mi) {
#pragma unroll
    for (int ni = 0; ni < 4; ++ni) {
      const int r0 = (int)row0 + wr + mi * 16 + lr * 4;
      const int c = (int)col0 + wc + ni * 16 + lc;
      f32x4 a = acc[mi][ni];
      if (EPI == 0) {
        float b = bias[c];
#pragma unroll
        for (int r = 0; r < 4; ++r) {
          float v = a[r] + b;
          unsigned short hh = f2bf(v);
          outH[(size_t)(r0 + r) * ldc + c] = hh;
          outL[(size_t)(r0 + r) * ldc + c] = f2bf(v - bf2f(hh));
        }
      } else if (EPI == 1) {
        float b = bias[c];
        us4 pk;
#pragma unroll
        for (int r = 0; r < 4; ++r) pk[r] = f2bf(a[r] + b);
        // v_t layout [batch][d=c][s]; rows are global s in [0,8192)
        *reinterpret_cast<us4*>(outH + ((size_t)(r0 >> 11) * 1024 + c) * 2048 + (r0 & 2047)) = pk;
      } else if (EPI == 2) {
#pragma unroll
        for (int r = 0; r < 4; ++r) outF[(size_t)(r0 + r) * ldc + c] = a[r];
      } else if (EPI == 3) {
#pragma unroll
        for (int r = 0; r < 4; ++r) outH[(size_t)(r0 + r) * ldc + c] = f2bf(a[r]);
      } else {
        float b = bias[c];
#pragma unroll
        for (int r = 0; r < 4; ++r) {
          size_t idx = (size_t)(r0 + r) * ldc + c;
          outF[idx] = a[r] + b + resid[idx];
        }
      }
    }
  }
}

// ---------------- row softmax: scores fp32 [rows][n] -> P bf16 ----------------
__global__ void __launch_bounds__(256) k_softmax(
    const float* __restrict__ S, unsigned short* __restrict__ P, int n) {
  __shared__ float red[4];
  const int row = blockIdx.x, tid = threadIdx.x;
  const int lane = tid & 63, wid = tid >> 6;
  const float* src = S + (size_t)row * n;
  float4 v0 = *reinterpret_cast<const float4*>(src + tid * 8);
  float4 v1 = *reinterpret_cast<const float4*>(src + tid * 8 + 4);
  float vv[8] = {v0.x, v0.y, v0.z, v0.w, v1.x, v1.y, v1.z, v1.w};
  float m = vv[0];
#pragma unroll
  for (int j = 1; j < 8; ++j) m = fmaxf(m, vv[j]);
#pragma unroll
  for (int o = 32; o > 0; o >>= 1) m = fmaxf(m, __shfl_xor(m, o));
  if (lane == 0) red[wid] = m;
  __syncthreads();
  m = fmaxf(fmaxf(red[0], red[1]), fmaxf(red[2], red[3]));
  __syncthreads();
  float e[8];
  float s = 0.f;
#pragma unroll
  for (int j = 0; j < 8; ++j) { e[j] = __expf(vv[j] - m); s += e[j]; }
#pragma unroll
  for (int o = 32; o > 0; o >>= 1) s += __shfl_xor(s, o);
  if (lane == 0) red[wid] = s;
  __syncthreads();
  s = red[0] + red[1] + red[2] + red[3];
  float inv = 1.0f / s;
  us4 p0, p1;
#pragma unroll
  for (int j = 0; j < 4; ++j) p0[j] = f2bf(e[j] * inv);
#pragma unroll
  for (int j = 0; j < 4; ++j) p1[j] = f2bf(e[j + 4] * inv);
  us4* dst = reinterpret_cast<us4*>(P + (size_t)row * n + tid * 8);
  dst[0] = p0;
  dst[1] = p1;
}

extern "C" void kernel_launch(void* const* d_in, const int* in_sizes, int n_in,
                              void* d_out, int out_size, void* d_ws, size_t ws_size,
                              hipStream_t stream) {
  (void)in_sizes; (void)n_in; (void)out_size; (void)ws_size;
  const float* x  = (const float*)d_in[0];
  const float* Wq = (const float*)d_in[1];
  const float* bq = (const float*)d_in[2];
  const float* Wk = (const float*)d_in[3];
  const float* bk = (const float*)d_in[4];
  const float* Wv = (const float*)d_in[5];
  const float* bv = (const float*)d_in[6];
  const float* Wo = (const float*)d_in[7];
  const float* bo = (const float*)d_in[8];
  float* out = (float*)d_out;

  char* p = (char*)d_ws;
  auto take = [&](size_t bytes) {
    char* r = p;
    p += (bytes + 255) & ~(size_t)255;
    return r;
  };
  const size_t SD = (size_t)4 * 2048 * 1024;  // 8388608 elements
  unsigned short* x_hi = (unsigned short*)take(SD * 2);
  unsigned short* x_lo = (unsigned short*)take(SD * 2);
  unsigned short* q_hi = (unsigned short*)take(SD * 2);
  unsigned short* q_lo = (unsigned short*)take(SD * 2);
  unsigned short* k_hi = (unsigned short*)take(SD * 2);
  unsigned short* k_lo = (unsigned short*)take(SD * 2);
  unsigned short* WqTh = (unsigned short*)take((size_t)1024 * 1024 * 2);
  unsigned short* WqTl = (unsigned short*)take((size_t)1024 * 1024 * 2);
  unsigned short* WkTh = (unsigned short*)take((size_t)1024 * 1024 * 2);
  unsigned short* WkTl = (unsigned short*)take((size_t)1024 * 1024 * 2);
  unsigned short* WvT  = (unsigned short*)take((size_t)1024 * 1024 * 2);
  unsigned short* WoT  = (unsigned short*)take((size_t)1024 * 1024 * 2);
  unsigned short* v_t  = (unsigned short*)take(SD * 2);   // [B][D][S] bf16
  unsigned short* attn = (unsigned short*)take(SD * 2);   // [B*S][D] bf16
  float* scores        = (float*)take((size_t)2048 * 2048 * 4);   // per-batch
  unsigned short* Pm   = (unsigned short*)take((size_t)2048 * 2048 * 2);

  dim3 blk(256);
  k_convert_split<<<dim3(8192), blk, 0, stream>>>(x, x_hi, x_lo, (int)(SD / 4));
  k_transpose_split<<<dim3(32, 32), blk, 0, stream>>>(Wq, WqTh, WqTl, 1024, 1);
  k_transpose_split<<<dim3(32, 32), blk, 0, stream>>>(Wk, WkTh, WkTl, 1024, 1);
  k_transpose_split<<<dim3(32, 32), blk, 0, stream>>>(Wv, WvT, nullptr, 1024, 0);
  k_transpose_split<<<dim3(32, 32), blk, 0, stream>>>(Wo, WoT, nullptr, 1024, 0);

  // projections
  k_gemm<1, 0><<<dim3(64, 8), blk, 0, stream>>>(x_hi, x_lo, WqTh, WqTl, 8192, 1024, 1024,
                                                bq, nullptr, nullptr, q_hi, q_lo, 1024);
  k_gemm<1, 0><<<dim3(64, 8), blk, 0, stream>>>(x_hi, x_lo, WkTh, WkTl, 8192, 1024, 1024,
                                                bk, nullptr, nullptr, k_hi, k_lo, 1024);
  k_gemm<0, 1><<<dim3(64, 8), blk, 0, stream>>>(x_hi, nullptr, WvT, nullptr, 8192, 1024, 1024,
                                                bv, nullptr, nullptr, v_t, nullptr, 2048);

  for (int b = 0; b < 4; ++b) {
    const size_t o = (size_t)b * 2048 * 1024;
    k_gemm<1, 2><<<dim3(16, 16), blk, 0, stream>>>(q_hi + o, q_lo + o, k_hi + o, k_lo + o,
                                                   2048, 2048, 1024, nullptr, nullptr,
                                                   scores, nullptr, nullptr, 2048);
    k_softmax<<<dim3(2048), blk, 0, stream>>>(scores, Pm, 2048);
    k_gemm<0, 3><<<dim3(16, 8), blk, 0, stream>>>(Pm, nullptr, v_t + o, nullptr,
                                                  2048, 1024, 2048, nullptr, nullptr,
                                                  nullptr, attn + o, nullptr, 1024);
  }
  k_gemm<0, 4><<<dim3(64, 8), blk, 0, stream>>>(attn, nullptr, WoT, nullptr, 8192, 1024, 1024,
                                                bo, x, out, nullptr, nullptr, 1024);
}

// Round 2
// 365.015 us; speedup vs baseline: 1.4687x; 1.4687x over previous
//
#include <hip/hip_runtime.h>
#include <hip/hip_bf16.h>

#define DEVI __device__ __forceinline__

typedef __attribute__((ext_vector_type(8))) short bf16x8;
typedef __attribute__((ext_vector_type(4))) float f32x4;
typedef __attribute__((ext_vector_type(4))) unsigned short us4;

DEVI unsigned short f2bf(float f) {
  union { float f; unsigned u; } v; v.f = f;
  unsigned r = v.u + 0x7fffu + ((v.u >> 16) & 1u);
  return (unsigned short)(r >> 16);
}
DEVI float bf2f(unsigned short h) {
  union { unsigned u; float f; } v; v.u = ((unsigned)h) << 16;
  return v.f;
}

// ---------------- elementwise split x -> x_hi, x_lo ----------------
__global__ void __launch_bounds__(256) k_convert_split(
    const float* __restrict__ x, unsigned short* __restrict__ hi,
    unsigned short* __restrict__ lo, int n4) {
  int i = blockIdx.x * 256 + threadIdx.x;
  if (i >= n4) return;
  float4 v = reinterpret_cast<const float4*>(x)[i];
  float vv[4] = {v.x, v.y, v.z, v.w};
  us4 h, l;
#pragma unroll
  for (int j = 0; j < 4; ++j) {
    unsigned short hh = f2bf(vv[j]);
    h[j] = hh;
    l[j] = f2bf(vv[j] - bf2f(hh));
  }
  reinterpret_cast<us4*>(hi)[i] = h;
  reinterpret_cast<us4*>(lo)[i] = l;
}

// ---------------- transpose weight [K][N] -> WT[N][K] (bf16 hi / optional lo) ----
__global__ void __launch_bounds__(256) k_transpose_split(
    const float* __restrict__ W, unsigned short* __restrict__ Thi,
    unsigned short* __restrict__ Tlo, int n, int split) {
  __shared__ float t[32][33];
  int tx = threadIdx.x & 31, ty = threadIdx.x >> 5;
  int n0 = blockIdx.x * 32, k0 = blockIdx.y * 32;
#pragma unroll
  for (int r = 0; r < 4; ++r)
    t[ty + r * 8][tx] = W[(size_t)(k0 + ty + r * 8) * n + n0 + tx];
  __syncthreads();
#pragma unroll
  for (int r = 0; r < 4; ++r) {
    int nn = n0 + ty + r * 8;
    float v = t[tx][ty + r * 8];
    unsigned short hh = f2bf(v);
    Thi[(size_t)nn * n + k0 + tx] = hh;
    if (split) Tlo[(size_t)nn * n + k0 + tx] = f2bf(v - bf2f(hh));
  }
}

// ---------------- GEMM: C[M][N] = A[M][K] * B_T[N][K]  (both bf16, contiguous K)
// SPLIT=1: acc = Ah*Bh + Ah*Bl + Al*Bh  (fp32-quality)
// EPI: 0 = bias + write split hi/lo bf16 (proj q,k)
//      1 = bias + write bf16 transposed to v_t[b][d][s]  (proj v)
//      2 = write fp32 (scores)
//      3 = write bf16 (attn = P*V)
//      4 = bias + residual + write fp32 (out proj)
DEVI void stage_tile(unsigned short* lbase, const unsigned short* g, int ldg,
                     int wid, int lane) {
#pragma unroll
  for (int it = 0; it < 2; ++it) {
    int chunk = it * 256 + wid * 64 + lane;
    int r = chunk >> 2, c = (chunk & 3) * 8;
    const unsigned short* gp = g + (size_t)r * ldg + c;
    unsigned short* lp = lbase + (it * 256 + wid * 64) * 8;  // wave-uniform
    __builtin_amdgcn_global_load_lds(
        (const __attribute__((address_space(1))) unsigned int*)gp,
        (__attribute__((address_space(3))) unsigned int*)lp, 16, 0, 0);
  }
}

template <int SPLIT, int EPI>
__global__ void __launch_bounds__(256, 4) k_gemm(
    const unsigned short* __restrict__ Ahi, const unsigned short* __restrict__ Alo,
    const unsigned short* __restrict__ Bhi, const unsigned short* __restrict__ Blo,
    int M, int N, int K, int ldA, int ldB,
    size_t azs, size_t bzs, size_t czs,
    const float* __restrict__ bias, const float* __restrict__ resid,
    float* __restrict__ outF, unsigned short* __restrict__ outH,
    unsigned short* __restrict__ outL, int ldc) {
  __shared__ unsigned short lds[(SPLIT ? 4 : 2) * 4096];
  unsigned short* Ah = lds;
  unsigned short* Al = SPLIT ? (lds + 4096) : lds;
  unsigned short* Bh = lds + (SPLIT ? 2 : 1) * 4096;
  unsigned short* Bl = SPLIT ? (lds + 3 * 4096) : lds;

  const int tid = threadIdx.x, lane = tid & 63, wid = tid >> 6;
  const int wr = (wid >> 1) * 64, wc = (wid & 1) * 64;
  const int lc = lane & 15, lr = lane >> 4;
  const int z = blockIdx.z;
  const size_t row0 = (size_t)blockIdx.x * 128, col0 = (size_t)blockIdx.y * 128;

  const unsigned short* Agh = Ahi + (size_t)z * azs + row0 * ldA;
  const unsigned short* Agl = SPLIT ? (Alo + (size_t)z * azs + row0 * ldA) : nullptr;
  const unsigned short* Bgh = Bhi + (size_t)z * bzs + col0 * ldB;
  const unsigned short* Bgl = SPLIT ? (Blo + (size_t)z * bzs + col0 * ldB) : nullptr;

  f32x4 acc[4][4] = {};

  for (int k0 = 0; k0 < K; k0 += 32) {
    stage_tile(Ah, Agh + k0, ldA, wid, lane);
    stage_tile(Bh, Bgh + k0, ldB, wid, lane);
    if (SPLIT) {
      stage_tile(Al, Agl + k0, ldA, wid, lane);
      stage_tile(Bl, Bgl + k0, ldB, wid, lane);
    }
    __syncthreads();
    bf16x8 ah[4], bh[4], al[4], bl[4];
#pragma unroll
    for (int i = 0; i < 4; ++i) {
      ah[i] = *reinterpret_cast<const bf16x8*>(Ah + (wr + i * 16 + lc) * 32 + lr * 8);
      bh[i] = *reinterpret_cast<const bf16x8*>(Bh + (wc + i * 16 + lc) * 32 + lr * 8);
      if (SPLIT) {
        al[i] = *reinterpret_cast<const bf16x8*>(Al + (wr + i * 16 + lc) * 32 + lr * 8);
        bl[i] = *reinterpret_cast<const bf16x8*>(Bl + (wc + i * 16 + lc) * 32 + lr * 8);
      }
    }
#pragma unroll
    for (int mi = 0; mi < 4; ++mi)
#pragma unroll
      for (int ni = 0; ni < 4; ++ni) {
        acc[mi][ni] = __builtin_amdgcn_mfma_f32_16x16x32_bf16(ah[mi], bh[ni], acc[mi][ni], 0, 0, 0);
        if (SPLIT) {
          acc[mi][ni] = __builtin_amdgcn_mfma_f32_16x16x32_bf16(ah[mi], bl[ni], acc[mi][ni], 0, 0, 0);
          acc[mi][ni] = __builtin_amdgcn_mfma_f32_16x16x32_bf16(al[mi], bh[ni], acc[mi][ni], 0, 0, 0);
        }
      }
    __syncthreads();
  }

#pragma unroll
  for (int mi = 0; mi < 4; ++mi) {
#pragma unroll
    for (int ni = 0; ni < 4; ++ni) {
      const int r0 = (int)row0 + wr + mi * 16 + lr * 4;
      const int c = (int)col0 + wc + ni * 16 + lc;
      f32x4 a = acc[mi][ni];
      if (EPI == 0) {
        float b = bias[c];
#pragma unroll
        for (int r = 0; r < 4; ++r) {
          float v = a[r] + b;
          unsigned short hh = f2bf(v);
          outH[(size_t)(r0 + r) * ldc + c] = hh;
          outL[(size_t)(r0 + r) * ldc + c] = f2bf(v - bf2f(hh));
        }
      } else if (EPI == 1) {
        float b = bias[c];
        us4 pk;
#pragma unroll
        for (int r = 0; r < 4; ++r) pk[r] = f2bf(a[r] + b);
        // v_t layout [batch][d=c][s]; rows are global s in [0,8192)
        *reinterpret_cast<us4*>(outH + ((size_t)(r0 >> 11) * 1024 + c) * 2048 + (r0 & 2047)) = pk;
      } else if (EPI == 2) {
#pragma unroll
        for (int r = 0; r < 4; ++r)
          outF[(size_t)z * czs + (size_t)(r0 + r) * ldc + c] = a[r];
      } else if (EPI == 3) {
#pragma unroll
        for (int r = 0; r < 4; ++r)
          outH[(size_t)z * czs + (size_t)(r0 + r) * ldc + c] = f2bf(a[r]);
      } else {
        float b = bias[c];
#pragma unroll
        for (int r = 0; r < 4; ++r) {
          size_t idx = (size_t)(r0 + r) * ldc + c;
          outF[idx] = a[r] + b + resid[idx];
        }
      }
    }
  }
}

// ---------------- row softmax: scores fp32 [rows][2048] -> P bf16 IN-PLACE ----
// P row b*2048+i is written over the first 4 KB of its own fp32 score row
// (each thread's reads complete before the first __syncthreads; writes happen
// after two more syncs, so in-place is race-free within the block).
__global__ void __launch_bounds__(256) k_softmax(
    const float* __restrict__ S, unsigned short* __restrict__ P) {
  __shared__ float red[4];
  const int row = blockIdx.x, tid = threadIdx.x;
  const int lane = tid & 63, wid = tid >> 6;
  const float* src = S + (size_t)row * 2048;
  float4 v0 = *reinterpret_cast<const float4*>(src + tid * 8);
  float4 v1 = *reinterpret_cast<const float4*>(src + tid * 8 + 4);
  float vv[8] = {v0.x, v0.y, v0.z, v0.w, v1.x, v1.y, v1.z, v1.w};
  float m = vv[0];
#pragma unroll
  for (int j = 1; j < 8; ++j) m = fmaxf(m, vv[j]);
#pragma unroll
  for (int o = 32; o > 0; o >>= 1) m = fmaxf(m, __shfl_xor(m, o));
  if (lane == 0) red[wid] = m;
  __syncthreads();
  m = fmaxf(fmaxf(red[0], red[1]), fmaxf(red[2], red[3]));
  __syncthreads();
  float e[8];
  float s = 0.f;
#pragma unroll
  for (int j = 0; j < 8; ++j) { e[j] = __expf(vv[j] - m); s += e[j]; }
#pragma unroll
  for (int o = 32; o > 0; o >>= 1) s += __shfl_xor(s, o);
  if (lane == 0) red[wid] = s;
  __syncthreads();
  s = red[0] + red[1] + red[2] + red[3];
  float inv = 1.0f / s;
  us4 p0, p1;
#pragma unroll
  for (int j = 0; j < 4; ++j) p0[j] = f2bf(e[j] * inv);
#pragma unroll
  for (int j = 0; j < 4; ++j) p1[j] = f2bf(e[j + 4] * inv);
  // P rows live at 4096-element (8192 B) stride inside the scores buffer
  us4* dst = reinterpret_cast<us4*>(P + (size_t)row * 4096 + tid * 8);
  dst[0] = p0;
  dst[1] = p1;
}

extern "C" void kernel_launch(void* const* d_in, const int* in_sizes, int n_in,
                              void* d_out, int out_size, void* d_ws, size_t ws_size,
                              hipStream_t stream) {
  (void)in_sizes; (void)n_in; (void)out_size;
  const float* x  = (const float*)d_in[0];
  const float* Wq = (const float*)d_in[1];
  const float* bq = (const float*)d_in[2];
  const float* Wk = (const float*)d_in[3];
  const float* bk = (const float*)d_in[4];
  const float* Wv = (const float*)d_in[5];
  const float* bv = (const float*)d_in[6];
  const float* Wo = (const float*)d_in[7];
  const float* bo = (const float*)d_in[8];
  float* out = (float*)d_out;

  char* p = (char*)d_ws;
  size_t used = 0;
  auto take = [&](size_t bytes) {
    char* r = p;
    size_t pad = (bytes + 255) & ~(size_t)255;
    p += pad;
    used += pad;
    return r;
  };
  const size_t SD = (size_t)4 * 2048 * 1024;  // 8388608 elements
  unsigned short* x_hi = (unsigned short*)take(SD * 2);
  unsigned short* x_lo = (unsigned short*)take(SD * 2);
  unsigned short* q_hi = (unsigned short*)take(SD * 2);
  unsigned short* q_lo = (unsigned short*)take(SD * 2);
  unsigned short* k_hi = (unsigned short*)take(SD * 2);
  unsigned short* k_lo = (unsigned short*)take(SD * 2);
  unsigned short* WqTh = (unsigned short*)take((size_t)1024 * 1024 * 2);
  unsigned short* WqTl = (unsigned short*)take((size_t)1024 * 1024 * 2);
  unsigned short* WkTh = (unsigned short*)take((size_t)1024 * 1024 * 2);
  unsigned short* WkTl = (unsigned short*)take((size_t)1024 * 1024 * 2);
  unsigned short* WvT  = (unsigned short*)take((size_t)1024 * 1024 * 2);
  unsigned short* WoT  = (unsigned short*)take((size_t)1024 * 1024 * 2);
  unsigned short* v_t  = (unsigned short*)take(SD * 2);   // [B][D][S] bf16
  unsigned short* attn = (unsigned short*)take(SD * 2);   // [B*S][D] bf16
  // batched scores if workspace allows, else per-batch
  const size_t SC_B = (size_t)2048 * 2048;  // elements per batch
  int nz = (ws_size - used >= 4 * SC_B * 4 + 4096) ? 4 : 1;
  float* scores = (float*)take((size_t)nz * SC_B * 4);  // P bf16 aliased in-place

  dim3 blk(256);
  k_convert_split<<<dim3(8192), blk, 0, stream>>>(x, x_hi, x_lo, (int)(SD / 4));
  k_transpose_split<<<dim3(32, 32), blk, 0, stream>>>(Wq, WqTh, WqTl, 1024, 1);
  k_transpose_split<<<dim3(32, 32), blk, 0, stream>>>(Wk, WkTh, WkTl, 1024, 1);
  k_transpose_split<<<dim3(32, 32), blk, 0, stream>>>(Wv, WvT, nullptr, 1024, 0);
  k_transpose_split<<<dim3(32, 32), blk, 0, stream>>>(Wo, WoT, nullptr, 1024, 0);

  // projections (z=1)
  k_gemm<1, 0><<<dim3(64, 8, 1), blk, 0, stream>>>(
      x_hi, x_lo, WqTh, WqTl, 8192, 1024, 1024, 1024, 1024, 0, 0, 0,
      bq, nullptr, nullptr, q_hi, q_lo, 1024);
  k_gemm<1, 0><<<dim3(64, 8, 1), blk, 0, stream>>>(
      x_hi, x_lo, WkTh, WkTl, 8192, 1024, 1024, 1024, 1024, 0, 0, 0,
      bk, nullptr, nullptr, k_hi, k_lo, 1024);
  k_gemm<0, 1><<<dim3(64, 8, 1), blk, 0, stream>>>(
      x_hi, nullptr, WvT, nullptr, 8192, 1024, 1024, 1024, 1024, 0, 0, 0,
      bv, nullptr, nullptr, v_t, nullptr, 2048);

  const size_t QZS = (size_t)2048 * 1024;   // q/k batch stride (elements)
  const size_t VZS = (size_t)1024 * 2048;   // v_t batch stride
  const size_t PZS = SC_B * 2;              // P batch stride in bf16 elements (aliased fp32 rows)
  for (int b0 = 0; b0 < 4; b0 += nz) {
    const size_t oq = (size_t)b0 * QZS;
    // scores = q . k^T   (split, fp32 out)
    k_gemm<1, 2><<<dim3(16, 16, nz), blk, 0, stream>>>(
        q_hi + oq, q_lo + oq, k_hi + oq, k_lo + oq, 2048, 2048, 1024, 1024, 1024,
        QZS, QZS, SC_B, nullptr, nullptr, scores, nullptr, nullptr, 2048);
    // softmax in-place (P bf16 overwrites score rows)
    k_softmax<<<dim3(2048 * nz), blk, 0, stream>>>(scores, (unsigned short*)scores);
    // attn = P . V   (P has ldA=4096 bf16 elements due to in-place aliasing)
    k_gemm<0, 3><<<dim3(16, 8, nz), blk, 0, stream>>>(
        (const unsigned short*)scores, nullptr, v_t + (size_t)b0 * VZS, nullptr,
        2048, 1024, 2048, 4096, 2048, PZS, VZS, QZS,
        nullptr, nullptr, nullptr, attn + oq, nullptr, 1024);
  }
  // out = attn . Wo^T + bo + x
  k_gemm<0, 4><<<dim3(64, 8, 1), blk, 0, stream>>>(
      attn, nullptr, WoT, nullptr, 8192, 1024, 1024, 1024, 1024, 0, 0, 0,
      bo, x, out, nullptr, nullptr, 1024);
}

// Round 3
// 329.993 us; speedup vs baseline: 1.6246x; 1.1061x over previous
//
#include <hip/hip_runtime.h>
#include <hip/hip_bf16.h>

#define DEVI __device__ __forceinline__

typedef __attribute__((ext_vector_type(8))) short bf16x8;
typedef __attribute__((ext_vector_type(4))) float f32x4;
typedef __attribute__((ext_vector_type(4))) unsigned short us4;

DEVI unsigned short f2bf(float f) {
  union { float f; unsigned u; } v; v.f = f;
  unsigned r = v.u + 0x7fffu + ((v.u >> 16) & 1u);
  return (unsigned short)(r >> 16);
}
DEVI float bf2f(unsigned short h) {
  union { unsigned u; float f; } v; v.u = ((unsigned)h) << 16;
  return v.f;
}

// ---------------- elementwise split x -> x_hi, x_lo ----------------
__global__ void __launch_bounds__(256) k_convert_split(
    const float* __restrict__ x, unsigned short* __restrict__ hi,
    unsigned short* __restrict__ lo, int n4) {
  int i = blockIdx.x * 256 + threadIdx.x;
  if (i >= n4) return;
  float4 v = reinterpret_cast<const float4*>(x)[i];
  float vv[4] = {v.x, v.y, v.z, v.w};
  us4 h, l;
#pragma unroll
  for (int j = 0; j < 4; ++j) {
    unsigned short hh = f2bf(vv[j]);
    h[j] = hh;
    l[j] = f2bf(vv[j] - bf2f(hh));
  }
  reinterpret_cast<us4*>(hi)[i] = h;
  reinterpret_cast<us4*>(lo)[i] = l;
}

// ---------------- transpose weight [K][N] -> WT[N][K] (bf16 hi / optional lo) ----
__global__ void __launch_bounds__(256) k_transpose_split(
    const float* __restrict__ W, unsigned short* __restrict__ Thi,
    unsigned short* __restrict__ Tlo, int n, int split) {
  __shared__ float t[32][33];
  int tx = threadIdx.x & 31, ty = threadIdx.x >> 5;
  int n0 = blockIdx.x * 32, k0 = blockIdx.y * 32;
#pragma unroll
  for (int r = 0; r < 4; ++r)
    t[ty + r * 8][tx] = W[(size_t)(k0 + ty + r * 8) * n + n0 + tx];
  __syncthreads();
#pragma unroll
  for (int r = 0; r < 4; ++r) {
    int nn = n0 + ty + r * 8;
    float v = t[tx][ty + r * 8];
    unsigned short hh = f2bf(v);
    Thi[(size_t)nn * n + k0 + tx] = hh;
    if (split) Tlo[(size_t)nn * n + k0 + tx] = f2bf(v - bf2f(hh));
  }
}

// ---------------- GEMM: C[M][N] = A[M][K] * B_T[N][K]  (both bf16, K-contiguous)
// Tiles [128 rows][64 K] bf16, XOR-swizzled: LDS slot (r,s) holds global chunk
// (r, s^(r&7)).  Stage: linear LDS dest + inverse-swizzled global source.
// Read: slot = (kk*4+lr) ^ (row&7)  -> conflict-free ds_read_b128.
DEVI void stage_tile64(unsigned short* lbase, const unsigned short* g, int ldg,
                       int wid, int lane) {
#pragma unroll
  for (int it = 0; it < 4; ++it) {
    int chunk = it * 256 + wid * 64 + lane;
    int r = chunk >> 3, s = chunk & 7;
    int c = (s ^ (r & 7)) * 8;
    const unsigned short* gp = g + (size_t)r * ldg + c;
    unsigned short* lp = lbase + (it * 256 + wid * 64) * 8;  // wave-uniform base
    __builtin_amdgcn_global_load_lds(
        (const __attribute__((address_space(1))) unsigned int*)gp,
        (__attribute__((address_space(3))) unsigned int*)lp, 16, 0, 0);
  }
}

DEVI bf16x8 frag(const unsigned short* base, int row, int kk, int lr) {
  int slot = (kk * 4 + lr) ^ (row & 7);
  return *reinterpret_cast<const bf16x8*>(base + row * 64 + slot * 8);
}

// SPLIT=1: acc = Ah*Bh + Ah*Bl + Al*Bh  (fp32-quality)
// EPI: 0 = bias + write split hi/lo bf16 (proj q,k)
//      1 = bias + write bf16 transposed to v_t[b][d][s]  (proj v)
//      2 = write fp32 (scores, z-strided)
//      3 = write bf16 (attn = P*V, z-strided)
//      4 = bias + residual + write fp32 (out proj)
template <int SPLIT, int EPI>
__global__ void __launch_bounds__(256, SPLIT ? 2 : 3) k_gemm(
    const unsigned short* __restrict__ Ahi, const unsigned short* __restrict__ Alo,
    const unsigned short* __restrict__ Bhi, const unsigned short* __restrict__ Blo,
    int K, int ldA, int ldB,
    size_t azs, size_t bzs, size_t czs,
    const float* __restrict__ bias, const float* __restrict__ resid,
    float* __restrict__ outF, unsigned short* __restrict__ outH,
    unsigned short* __restrict__ outL, int ldc) {
  __shared__ unsigned short lds[(SPLIT ? 4 : 2) * 8192];
  unsigned short* Ah = lds;
  unsigned short* Al = SPLIT ? (lds + 8192) : lds;
  unsigned short* Bh = lds + (SPLIT ? 2 : 1) * 8192;
  unsigned short* Bl = SPLIT ? (lds + 3 * 8192) : lds;

  // bijective chunked XCD swizzle (all launch grids have nwg % 8 == 0)
  const int gx = gridDim.x, gy = gridDim.y;
  const int nwg = gx * gy * gridDim.z;
  const int l = (blockIdx.z * gy + blockIdx.y) * gx + blockIdx.x;
  const int nl = (l & 7) * (nwg >> 3) + (l >> 3);
  const int bx = nl % gx;
  const int rem = nl / gx;
  const int by = rem % gy;
  const int z = rem / gy;

  const int tid = threadIdx.x, lane = tid & 63, wid = tid >> 6;
  const int wr = (wid >> 1) * 64, wc = (wid & 1) * 64;
  const int lc = lane & 15, lr = lane >> 4;
  const size_t row0 = (size_t)bx * 128, col0 = (size_t)by * 128;

  const unsigned short* Agh = Ahi + (size_t)z * azs + row0 * ldA;
  const unsigned short* Agl = SPLIT ? (Alo + (size_t)z * azs + row0 * ldA) : nullptr;
  const unsigned short* Bgh = Bhi + (size_t)z * bzs + col0 * ldB;
  const unsigned short* Bgl = SPLIT ? (Blo + (size_t)z * bzs + col0 * ldB) : nullptr;

  f32x4 acc[4][4] = {};

  for (int k0 = 0; k0 < K; k0 += 64) {
    stage_tile64(Ah, Agh + k0, ldA, wid, lane);
    stage_tile64(Bh, Bgh + k0, ldB, wid, lane);
    if (SPLIT) {
      stage_tile64(Al, Agl + k0, ldA, wid, lane);
      stage_tile64(Bl, Bgl + k0, ldB, wid, lane);
    }
    __syncthreads();
#pragma unroll
    for (int kk = 0; kk < 2; ++kk) {
      bf16x8 ah[4], bh[4], al[4], bl[4];
#pragma unroll
      for (int i = 0; i < 4; ++i) {
        ah[i] = frag(Ah, wr + i * 16 + lc, kk, lr);
        bh[i] = frag(Bh, wc + i * 16 + lc, kk, lr);
        if (SPLIT) {
          al[i] = frag(Al, wr + i * 16 + lc, kk, lr);
          bl[i] = frag(Bl, wc + i * 16 + lc, kk, lr);
        }
      }
#pragma unroll
      for (int mi = 0; mi < 4; ++mi)
#pragma unroll
        for (int ni = 0; ni < 4; ++ni)
          acc[mi][ni] = __builtin_amdgcn_mfma_f32_16x16x32_bf16(ah[mi], bh[ni], acc[mi][ni], 0, 0, 0);
      if (SPLIT) {
#pragma unroll
        for (int mi = 0; mi < 4; ++mi)
#pragma unroll
          for (int ni = 0; ni < 4; ++ni)
            acc[mi][ni] = __builtin_amdgcn_mfma_f32_16x16x32_bf16(ah[mi], bl[ni], acc[mi][ni], 0, 0, 0);
#pragma unroll
        for (int mi = 0; mi < 4; ++mi)
#pragma unroll
          for (int ni = 0; ni < 4; ++ni)
            acc[mi][ni] = __builtin_amdgcn_mfma_f32_16x16x32_bf16(al[mi], bh[ni], acc[mi][ni], 0, 0, 0);
      }
    }
    __syncthreads();
  }

#pragma unroll
  for (int mi = 0; mi < 4; ++mi) {
#pragma unroll
    for (int ni = 0; ni < 4; ++ni) {
      const int r0 = (int)row0 + wr + mi * 16 + lr * 4;
      const int c = (int)col0 + wc + ni * 16 + lc;
      f32x4 a = acc[mi][ni];
      if (EPI == 0) {
        float b = bias[c];
#pragma unroll
        for (int r = 0; r < 4; ++r) {
          float v = a[r] + b;
          unsigned short hh = f2bf(v);
          outH[(size_t)(r0 + r) * ldc + c] = hh;
          outL[(size_t)(r0 + r) * ldc + c] = f2bf(v - bf2f(hh));
        }
      } else if (EPI == 1) {
        float b = bias[c];
        us4 pk;
#pragma unroll
        for (int r = 0; r < 4; ++r) pk[r] = f2bf(a[r] + b);
        // v_t layout [batch][d=c][s]; rows are global s in [0,8192)
        *reinterpret_cast<us4*>(outH + ((size_t)(r0 >> 11) * 1024 + c) * 2048 + (r0 & 2047)) = pk;
      } else if (EPI == 2) {
#pragma unroll
        for (int r = 0; r < 4; ++r)
          outF[(size_t)z * czs + (size_t)(r0 + r) * ldc + c] = a[r];
      } else if (EPI == 3) {
#pragma unroll
        for (int r = 0; r < 4; ++r)
          outH[(size_t)z * czs + (size_t)(r0 + r) * ldc + c] = f2bf(a[r]);
      } else {
        float b = bias[c];
#pragma unroll
        for (int r = 0; r < 4; ++r) {
          size_t idx = (size_t)(r0 + r) * ldc + c;
          outF[idx] = a[r] + b + resid[idx];
        }
      }
    }
  }
}

// ---------------- row softmax: scores fp32 [rows][2048] -> P bf16 IN-PLACE ----
__global__ void __launch_bounds__(256) k_softmax(
    const float* __restrict__ S, unsigned short* __restrict__ P) {
  __shared__ float red[4];
  const int row = blockIdx.x, tid = threadIdx.x;
  const int lane = tid & 63, wid = tid >> 6;
  const float* src = S + (size_t)row * 2048;
  float4 v0 = *reinterpret_cast<const float4*>(src + tid * 8);
  float4 v1 = *reinterpret_cast<const float4*>(src + tid * 8 + 4);
  float vv[8] = {v0.x, v0.y, v0.z, v0.w, v1.x, v1.y, v1.z, v1.w};
  float m = vv[0];
#pragma unroll
  for (int j = 1; j < 8; ++j) m = fmaxf(m, vv[j]);
#pragma unroll
  for (int o = 32; o > 0; o >>= 1) m = fmaxf(m, __shfl_xor(m, o));
  if (lane == 0) red[wid] = m;
  __syncthreads();
  m = fmaxf(fmaxf(red[0], red[1]), fmaxf(red[2], red[3]));
  __syncthreads();
  float e[8];
  float s = 0.f;
#pragma unroll
  for (int j = 0; j < 8; ++j) { e[j] = __expf(vv[j] - m); s += e[j]; }
#pragma unroll
  for (int o = 32; o > 0; o >>= 1) s += __shfl_xor(s, o);
  if (lane == 0) red[wid] = s;
  __syncthreads();
  s = red[0] + red[1] + red[2] + red[3];
  float inv = 1.0f / s;
  us4 p0, p1;
#pragma unroll
  for (int j = 0; j < 4; ++j) p0[j] = f2bf(e[j] * inv);
#pragma unroll
  for (int j = 0; j < 4; ++j) p1[j] = f2bf(e[j + 4] * inv);
  // P rows live at 4096-element (8192 B) stride inside the scores buffer
  us4* dst = reinterpret_cast<us4*>(P + (size_t)row * 4096 + tid * 8);
  dst[0] = p0;
  dst[1] = p1;
}

extern "C" void kernel_launch(void* const* d_in, const int* in_sizes, int n_in,
                              void* d_out, int out_size, void* d_ws, size_t ws_size,
                              hipStream_t stream) {
  (void)in_sizes; (void)n_in; (void)out_size;
  const float* x  = (const float*)d_in[0];
  const float* Wq = (const float*)d_in[1];
  const float* bq = (const float*)d_in[2];
  const float* Wk = (const float*)d_in[3];
  const float* bk = (const float*)d_in[4];
  const float* Wv = (const float*)d_in[5];
  const float* bv = (const float*)d_in[6];
  const float* Wo = (const float*)d_in[7];
  const float* bo = (const float*)d_in[8];
  float* out = (float*)d_out;

  char* p = (char*)d_ws;
  size_t used = 0;
  auto take = [&](size_t bytes) {
    char* r = p;
    size_t pad = (bytes + 255) & ~(size_t)255;
    p += pad;
    used += pad;
    return r;
  };
  const size_t SD = (size_t)4 * 2048 * 1024;  // 8388608 elements
  unsigned short* x_hi = (unsigned short*)take(SD * 2);
  unsigned short* x_lo = (unsigned short*)take(SD * 2);
  unsigned short* q_hi = (unsigned short*)take(SD * 2);
  unsigned short* q_lo = (unsigned short*)take(SD * 2);
  unsigned short* k_hi = (unsigned short*)take(SD * 2);
  unsigned short* k_lo = (unsigned short*)take(SD * 2);
  unsigned short* WqTh = (unsigned short*)take((size_t)1024 * 1024 * 2);
  unsigned short* WqTl = (unsigned short*)take((size_t)1024 * 1024 * 2);
  unsigned short* WkTh = (unsigned short*)take((size_t)1024 * 1024 * 2);
  unsigned short* WkTl = (unsigned short*)take((size_t)1024 * 1024 * 2);
  unsigned short* WvT  = (unsigned short*)take((size_t)1024 * 1024 * 2);
  unsigned short* WoT  = (unsigned short*)take((size_t)1024 * 1024 * 2);
  unsigned short* v_t  = (unsigned short*)take(SD * 2);   // [B][D][S] bf16
  unsigned short* attn = (unsigned short*)take(SD * 2);   // [B*S][D] bf16
  const size_t SC_B = (size_t)2048 * 2048;  // score elements per batch
  int nz = (ws_size - used >= 4 * SC_B * 4 + 4096) ? 4 : 1;
  float* scores = (float*)take((size_t)nz * SC_B * 4);  // P bf16 aliased in-place

  dim3 blk(256);
  k_convert_split<<<dim3(8192), blk, 0, stream>>>(x, x_hi, x_lo, (int)(SD / 4));
  k_transpose_split<<<dim3(32, 32), blk, 0, stream>>>(Wq, WqTh, WqTl, 1024, 1);
  k_transpose_split<<<dim3(32, 32), blk, 0, stream>>>(Wk, WkTh, WkTl, 1024, 1);
  k_transpose_split<<<dim3(32, 32), blk, 0, stream>>>(Wv, WvT, nullptr, 1024, 0);
  k_transpose_split<<<dim3(32, 32), blk, 0, stream>>>(Wo, WoT, nullptr, 1024, 0);

  // projections
  k_gemm<1, 0><<<dim3(64, 8, 1), blk, 0, stream>>>(
      x_hi, x_lo, WqTh, WqTl, 1024, 1024, 1024, 0, 0, 0,
      bq, nullptr, nullptr, q_hi, q_lo, 1024);
  k_gemm<1, 0><<<dim3(64, 8, 1), blk, 0, stream>>>(
      x_hi, x_lo, WkTh, WkTl, 1024, 1024, 1024, 0, 0, 0,
      bk, nullptr, nullptr, k_hi, k_lo, 1024);
  k_gemm<0, 1><<<dim3(64, 8, 1), blk, 0, stream>>>(
      x_hi, nullptr, WvT, nullptr, 1024, 1024, 1024, 0, 0, 0,
      bv, nullptr, nullptr, v_t, nullptr, 2048);

  const size_t QZS = (size_t)2048 * 1024;   // q/k batch stride (elements)
  const size_t VZS = (size_t)1024 * 2048;   // v_t batch stride
  const size_t PZS = SC_B * 2;              // P batch stride in bf16 elements
  for (int b0 = 0; b0 < 4; b0 += nz) {
    const size_t oq = (size_t)b0 * QZS;
    // scores = q . k^T   (split, fp32 out)
    k_gemm<1, 2><<<dim3(16, 16, nz), blk, 0, stream>>>(
        q_hi + oq, q_lo + oq, k_hi + oq, k_lo + oq, 1024, 1024, 1024,
        QZS, QZS, SC_B, nullptr, nullptr, scores, nullptr, nullptr, 2048);
    // softmax in-place (P bf16 overwrites score rows)
    k_softmax<<<dim3(2048 * nz), blk, 0, stream>>>(scores, (unsigned short*)scores);
    // attn = P . V   (P has ldA=4096 bf16 elements due to in-place aliasing)
    k_gemm<0, 3><<<dim3(16, 8, nz), blk, 0, stream>>>(
        (const unsigned short*)scores, nullptr, v_t + (size_t)b0 * VZS, nullptr,
        2048, 4096, 2048, PZS, VZS, QZS,
        nullptr, nullptr, nullptr, attn + oq, nullptr, 1024);
  }
  // out = attn . Wo^T + bo + x
  k_gemm<0, 4><<<dim3(64, 8, 1), blk, 0, stream>>>(
      attn, nullptr, WoT, nullptr, 1024, 1024, 1024, 0, 0, 0,
      bo, x, out, nullptr, nullptr, 1024);
}

// Round 4
// 230.169 us; speedup vs baseline: 2.3292x; 1.4337x over previous
//
#include <hip/hip_runtime.h>
#include <hip/hip_bf16.h>

#define DEVI __device__ __forceinline__

typedef __attribute__((ext_vector_type(8))) _Float16 f16x8;
typedef __attribute__((ext_vector_type(4))) float f32x4;
typedef __attribute__((ext_vector_type(4))) unsigned short us4;

DEVI unsigned short f2h(float f) {
  union { _Float16 h; unsigned short u; } v;
  v.h = (_Float16)f;
  return v.u;
}

// ---------------- elementwise convert x -> fp16 ----------------
__global__ void __launch_bounds__(256) k_convert_f16(
    const float* __restrict__ x, unsigned short* __restrict__ o, int n4) {
  int i = blockIdx.x * 256 + threadIdx.x;
  if (i >= n4) return;
  float4 v = reinterpret_cast<const float4*>(x)[i];
  us4 h;
  h[0] = f2h(v.x); h[1] = f2h(v.y); h[2] = f2h(v.z); h[3] = f2h(v.w);
  reinterpret_cast<us4*>(o)[i] = h;
}

// ---------------- transpose weight [K][N] -> WT[N][K] fp16 ----------------
__global__ void __launch_bounds__(256) k_transpose_f16(
    const float* __restrict__ W, unsigned short* __restrict__ T, int n) {
  __shared__ float t[32][33];
  int tx = threadIdx.x & 31, ty = threadIdx.x >> 5;
  int n0 = blockIdx.x * 32, k0 = blockIdx.y * 32;
#pragma unroll
  for (int r = 0; r < 4; ++r)
    t[ty + r * 8][tx] = W[(size_t)(k0 + ty + r * 8) * n + n0 + tx];
  __syncthreads();
#pragma unroll
  for (int r = 0; r < 4; ++r) {
    int nn = n0 + ty + r * 8;
    T[(size_t)nn * n + k0 + tx] = f2h(t[tx][ty + r * 8]);
  }
}

// ---------------- GEMM: C[M][N] = A[M][K] * B_T[N][K]  (fp16, K-contiguous)
// Tiles [128 rows][64 K], XOR-swizzled: LDS slot (r,s) holds global chunk
// (r, s^(r&7)).  Stage: linear LDS dest + inverse-swizzled global source.
// Read: slot = (kk*4+lr) ^ (row&7)  -> conflict-free ds_read_b128.
DEVI void stage_tile64(unsigned short* lbase, const unsigned short* g, int ldg,
                       int wid, int lane) {
#pragma unroll
  for (int it = 0; it < 4; ++it) {
    int chunk = it * 256 + wid * 64 + lane;
    int r = chunk >> 3, s = chunk & 7;
    int c = (s ^ (r & 7)) * 8;
    const unsigned short* gp = g + (size_t)r * ldg + c;
    unsigned short* lp = lbase + (it * 256 + wid * 64) * 8;  // wave-uniform base
    __builtin_amdgcn_global_load_lds(
        (const __attribute__((address_space(1))) unsigned int*)gp,
        (__attribute__((address_space(3))) unsigned int*)lp, 16, 0, 0);
  }
}

DEVI f16x8 frag(const unsigned short* base, int row, int kk, int lr) {
  int slot = (kk * 4 + lr) ^ (row & 7);
  return *reinterpret_cast<const f16x8*>(base + row * 64 + slot * 8);
}

// EPI: 0 = bias + write fp16 (proj q,k)
//      1 = bias + write fp16 transposed to v_t[b][d][s]  (proj v)
//      2 = write fp32 (scores, z-strided)
//      3 = write fp16 (attn = P*V, z-strided)
//      4 = bias + residual + write fp32 (out proj)
template <int EPI>
__global__ void __launch_bounds__(256, 4) k_gemm(
    const unsigned short* __restrict__ A, const unsigned short* __restrict__ B,
    int K, int ldA, int ldB,
    size_t azs, size_t bzs, size_t czs,
    const float* __restrict__ bias, const float* __restrict__ resid,
    float* __restrict__ outF, unsigned short* __restrict__ outH, int ldc) {
  __shared__ unsigned short lds[2 * 8192];
  unsigned short* Alds = lds;
  unsigned short* Blds = lds + 8192;

  // bijective chunked XCD swizzle (all launch grids have nwg % 8 == 0)
  const int gx = gridDim.x, gy = gridDim.y;
  const int nwg = gx * gy * gridDim.z;
  const int l = (blockIdx.z * gy + blockIdx.y) * gx + blockIdx.x;
  const int nl = (l & 7) * (nwg >> 3) + (l >> 3);
  const int bx = nl % gx;
  const int rem = nl / gx;
  const int by = rem % gy;
  const int z = rem / gy;

  const int tid = threadIdx.x, lane = tid & 63, wid = tid >> 6;
  const int wr = (wid >> 1) * 64, wc = (wid & 1) * 64;
  const int lc = lane & 15, lr = lane >> 4;
  const size_t row0 = (size_t)bx * 128, col0 = (size_t)by * 128;

  const unsigned short* Ag = A + (size_t)z * azs + row0 * ldA;
  const unsigned short* Bg = B + (size_t)z * bzs + col0 * ldB;

  f32x4 acc[4][4] = {};

  for (int k0 = 0; k0 < K; k0 += 64) {
    stage_tile64(Alds, Ag + k0, ldA, wid, lane);
    stage_tile64(Blds, Bg + k0, ldB, wid, lane);
    __syncthreads();
#pragma unroll
    for (int kk = 0; kk < 2; ++kk) {
      f16x8 af[4], bf[4];
#pragma unroll
      for (int i = 0; i < 4; ++i) {
        af[i] = frag(Alds, wr + i * 16 + lc, kk, lr);
        bf[i] = frag(Blds, wc + i * 16 + lc, kk, lr);
      }
#pragma unroll
      for (int mi = 0; mi < 4; ++mi)
#pragma unroll
        for (int ni = 0; ni < 4; ++ni)
          acc[mi][ni] = __builtin_amdgcn_mfma_f32_16x16x32_f16(af[mi], bf[ni], acc[mi][ni], 0, 0, 0);
    }
    __syncthreads();
  }

#pragma unroll
  for (int mi = 0; mi < 4; ++mi) {
#pragma unroll
    for (int ni = 0; ni < 4; ++ni) {
      const int r0 = (int)row0 + wr + mi * 16 + lr * 4;
      const int c = (int)col0 + wc + ni * 16 + lc;
      f32x4 a = acc[mi][ni];
      if (EPI == 0) {
        float b = bias[c];
#pragma unroll
        for (int r = 0; r < 4; ++r)
          outH[(size_t)(r0 + r) * ldc + c] = f2h(a[r] + b);
      } else if (EPI == 1) {
        float b = bias[c];
        us4 pk;
#pragma unroll
        for (int r = 0; r < 4; ++r) pk[r] = f2h(a[r] + b);
        // v_t layout [batch][d=c][s]; rows are global s in [0,8192)
        *reinterpret_cast<us4*>(outH + ((size_t)(r0 >> 11) * 1024 + c) * 2048 + (r0 & 2047)) = pk;
      } else if (EPI == 2) {
#pragma unroll
        for (int r = 0; r < 4; ++r)
          outF[(size_t)z * czs + (size_t)(r0 + r) * ldc + c] = a[r];
      } else if (EPI == 3) {
#pragma unroll
        for (int r = 0; r < 4; ++r)
          outH[(size_t)z * czs + (size_t)(r0 + r) * ldc + c] = f2h(a[r]);
      } else {
        float b = bias[c];
#pragma unroll
        for (int r = 0; r < 4; ++r) {
          size_t idx = (size_t)(r0 + r) * ldc + c;
          outF[idx] = a[r] + b + resid[idx];
        }
      }
    }
  }
}

// ---------------- row softmax: scores fp32 [rows][2048] -> P fp16 IN-PLACE ----
// P row is written over the first 4 KB of its own fp32 score row; reads of the
// whole row complete before the writes (separated by two __syncthreads).
__global__ void __launch_bounds__(256) k_softmax(
    const float* __restrict__ S, unsigned short* __restrict__ P) {
  __shared__ float red[4];
  const int row = blockIdx.x, tid = threadIdx.x;
  const int lane = tid & 63, wid = tid >> 6;
  const float* src = S + (size_t)row * 2048;
  float4 v0 = *reinterpret_cast<const float4*>(src + tid * 8);
  float4 v1 = *reinterpret_cast<const float4*>(src + tid * 8 + 4);
  float vv[8] = {v0.x, v0.y, v0.z, v0.w, v1.x, v1.y, v1.z, v1.w};
  float m = vv[0];
#pragma unroll
  for (int j = 1; j < 8; ++j) m = fmaxf(m, vv[j]);
#pragma unroll
  for (int o = 32; o > 0; o >>= 1) m = fmaxf(m, __shfl_xor(m, o));
  if (lane == 0) red[wid] = m;
  __syncthreads();
  m = fmaxf(fmaxf(red[0], red[1]), fmaxf(red[2], red[3]));
  __syncthreads();
  float e[8];
  float s = 0.f;
#pragma unroll
  for (int j = 0; j < 8; ++j) { e[j] = __expf(vv[j] - m); s += e[j]; }
#pragma unroll
  for (int o = 32; o > 0; o >>= 1) s += __shfl_xor(s, o);
  if (lane == 0) red[wid] = s;
  __syncthreads();
  s = red[0] + red[1] + red[2] + red[3];
  float inv = 1.0f / s;
  us4 p0, p1;
#pragma unroll
  for (int j = 0; j < 4; ++j) p0[j] = f2h(e[j] * inv);
#pragma unroll
  for (int j = 0; j < 4; ++j) p1[j] = f2h(e[j + 4] * inv);
  // P rows live at 4096-element (8192 B) stride inside the scores buffer
  us4* dst = reinterpret_cast<us4*>(P + (size_t)row * 4096 + tid * 8);
  dst[0] = p0;
  dst[1] = p1;
}

extern "C" void kernel_launch(void* const* d_in, const int* in_sizes, int n_in,
                              void* d_out, int out_size, void* d_ws, size_t ws_size,
                              hipStream_t stream) {
  (void)in_sizes; (void)n_in; (void)out_size;
  const float* x  = (const float*)d_in[0];
  const float* Wq = (const float*)d_in[1];
  const float* bq = (const float*)d_in[2];
  const float* Wk = (const float*)d_in[3];
  const float* bk = (const float*)d_in[4];
  const float* Wv = (const float*)d_in[5];
  const float* bv = (const float*)d_in[6];
  const float* Wo = (const float*)d_in[7];
  const float* bo = (const float*)d_in[8];
  float* out = (float*)d_out;

  char* p = (char*)d_ws;
  size_t used = 0;
  auto take = [&](size_t bytes) {
    char* r = p;
    size_t pad = (bytes + 255) & ~(size_t)255;
    p += pad;
    used += pad;
    return r;
  };
  const size_t SD = (size_t)4 * 2048 * 1024;  // 8388608 elements
  unsigned short* x_h  = (unsigned short*)take(SD * 2);
  unsigned short* q_h  = (unsigned short*)take(SD * 2);
  unsigned short* k_h  = (unsigned short*)take(SD * 2);
  unsigned short* WqT  = (unsigned short*)take((size_t)1024 * 1024 * 2);
  unsigned short* WkT  = (unsigned short*)take((size_t)1024 * 1024 * 2);
  unsigned short* WvT  = (unsigned short*)take((size_t)1024 * 1024 * 2);
  unsigned short* WoT  = (unsigned short*)take((size_t)1024 * 1024 * 2);
  unsigned short* v_t  = (unsigned short*)take(SD * 2);   // [B][D][S] fp16
  unsigned short* attn = (unsigned short*)take(SD * 2);   // [B*S][D] fp16
  const size_t SC_B = (size_t)2048 * 2048;  // score elements per batch
  int nz = (ws_size - used >= 4 * SC_B * 4 + 4096) ? 4 : 1;
  float* scores = (float*)take((size_t)nz * SC_B * 4);  // P fp16 aliased in-place

  dim3 blk(256);
  k_convert_f16<<<dim3(8192), blk, 0, stream>>>(x, x_h, (int)(SD / 4));
  k_transpose_f16<<<dim3(32, 32), blk, 0, stream>>>(Wq, WqT, 1024);
  k_transpose_f16<<<dim3(32, 32), blk, 0, stream>>>(Wk, WkT, 1024);
  k_transpose_f16<<<dim3(32, 32), blk, 0, stream>>>(Wv, WvT, 1024);
  k_transpose_f16<<<dim3(32, 32), blk, 0, stream>>>(Wo, WoT, 1024);

  // projections
  k_gemm<0><<<dim3(64, 8, 1), blk, 0, stream>>>(
      x_h, WqT, 1024, 1024, 1024, 0, 0, 0, bq, nullptr, nullptr, q_h, 1024);
  k_gemm<0><<<dim3(64, 8, 1), blk, 0, stream>>>(
      x_h, WkT, 1024, 1024, 1024, 0, 0, 0, bk, nullptr, nullptr, k_h, 1024);
  k_gemm<1><<<dim3(64, 8, 1), blk, 0, stream>>>(
      x_h, WvT, 1024, 1024, 1024, 0, 0, 0, bv, nullptr, nullptr, v_t, 2048);

  const size_t QZS = (size_t)2048 * 1024;   // q/k batch stride (elements)
  const size_t VZS = (size_t)1024 * 2048;   // v_t batch stride
  const size_t PZS = SC_B * 2;              // P batch stride in fp16 elements
  for (int b0 = 0; b0 < 4; b0 += nz) {
    const size_t oq = (size_t)b0 * QZS;
    // scores = q . k^T  (fp32 out)
    k_gemm<2><<<dim3(16, 16, nz), blk, 0, stream>>>(
        q_h + oq, k_h + oq, 1024, 1024, 1024,
        QZS, QZS, SC_B, nullptr, nullptr, scores, nullptr, 2048);
    // softmax in-place (P fp16 overwrites score rows)
    k_softmax<<<dim3(2048 * nz), blk, 0, stream>>>(scores, (unsigned short*)scores);
    // attn = P . V   (P has ldA=4096 fp16 elements due to in-place aliasing)
    k_gemm<3><<<dim3(16, 8, nz), blk, 0, stream>>>(
        (const unsigned short*)scores, v_t + (size_t)b0 * VZS,
        2048, 4096, 2048, PZS, VZS, QZS,
        nullptr, nullptr, nullptr, attn + oq, 1024);
  }
  // out = attn . Wo^T + bo + x
  k_gemm<4><<<dim3(64, 8, 1), blk, 0, stream>>>(
      attn, WoT, 1024, 1024, 1024, 0, 0, 0, bo, x, out, nullptr, 1024);
}